// Round 1
// 1200.261 us; speedup vs baseline: 1.2067x; 1.2067x over previous
//
#include <hip/hip_runtime.h>
#include <hip/hip_bf16.h>
#include <math.h>

typedef __hip_bfloat16 bf16;
typedef __attribute__((ext_vector_type(8))) short bf16x8;   // 8 bf16 = 4 VGPR
typedef __attribute__((ext_vector_type(4))) float f32x4;    // MFMA acc

#define BATCH   16
#define SEQLEN  2048
#define INDIM   64
#define HIDD    256
#define STATE_D 256
#define MLPD    1024
#define OUTD    128
#define NLAYERS 4
#define M_TOK   (BATCH*SEQLEN)     // 32768 tokens
#define CHUNK   64
#define NCHUNK  (SEQLEN/CHUNK)     // 32 chunks per batch

// ---- fp32 masters (residual chain precision) -------------------------------
__device__ float g_h [(size_t)M_TOK*256];
__device__ float g_y [(size_t)M_TOK*256];
__device__ float g_bu[(size_t)M_TOK*512];
__device__ float g_carry[512*512];
// ---- bf16 shadows / packed weights (MFMA operands) -------------------------
__device__ bf16  g_hb [(size_t)M_TOK*256];
__device__ bf16  g_yb [(size_t)M_TOK*256];
__device__ bf16  g_bub[(size_t)M_TOK*512];
__device__ bf16  g_zb [(size_t)M_TOK*1024];
__device__ bf16  g_Bnb[512*256];    // B_norm: rows 0-255 re, 256-511 im
__device__ bf16  g_Cwb[256*512];    // [Cre | -Cim]
__device__ bf16  g_Whb[1024*256];   // layer-local Wh
__device__ bf16  g_Wob[256*1024];   // layer-local Wo

#define SF_H  0
#define SF_Y  1
#define SF_BU 2
#define SB_HB  0
#define SB_YB  1
#define SB_BUB 2
#define SB_ZB  3
#define SB_BNB 4
#define SB_CWB 5
#define SB_WHB 6
#define SB_WOB 7

__device__ __forceinline__ float* buff(int sel){
  switch(sel){ case SF_H: return g_h; case SF_Y: return g_y; default: return g_bu; }
}
__device__ __forceinline__ bf16* bufb(int sel){
  switch(sel){
    case SB_HB:  return g_hb;  case SB_YB:  return g_yb;
    case SB_BUB: return g_bub; case SB_ZB:  return g_zb;
    case SB_BNB: return g_Bnb; case SB_CWB: return g_Cwb;
    case SB_WHB: return g_Whb; default:     return g_Wob; }
}

// async global->LDS, 16B per lane. LDS dest is wave-uniform base + lane*16.
__device__ __forceinline__ void gld_lds16(const void* g, void* l){
  __builtin_amdgcn_global_load_lds(
      (const __attribute__((address_space(1))) unsigned int*)g,
      (__attribute__((address_space(3))) unsigned int*)l, 16, 0, 0);
}

// ---------------------------------------------------------------------------
// MFMA GEMM: C[M,N] = act(A @ W^T + bias) (+res / +dscale*res)
// A: bf16 [M,K] lda;  W: bf16 [N,K] ldw.  128x128 block, 4 waves, BK=32.
// m97 structure: linear LDS [128][32] bf16 (16 KB total), global_load_lds
// width=16 staging (wave-uniform LDS base, per-lane global addr), 2-barrier
// K-loop. Bijective XCD-chunked blockIdx swizzle for L2 reuse of the A panel
// across column-blocks.
// FLAGS: 1=bias  2=add res  4=add dscale[n]*res.  ACT: 1=exact GELU.
// ---------------------------------------------------------------------------
template<int ACT, int FLAGS>
__global__ __launch_bounds__(256) void mfma_gemm(
    int aSel, int lda, int wSel, int ldw,
    int oFSel, int oBSel, int ldc,
    const float* __restrict__ bias,
    int rSel, int ldres,
    const float* __restrict__ dscale,
    int K)
{
  const bf16* A = bufb(aSel);
  const bf16* W = bufb(wSel);
  float* OF = (oFSel >= 0) ? buff(oFSel) : nullptr;
  bf16*  OB = (oBSel >= 0) ? bufb(oBSel) : nullptr;
  const float* res = (rSel >= 0) ? buff(rSel) : nullptr;

  __shared__ __align__(16) unsigned short As[128*32];   // 8 KB
  __shared__ __align__(16) unsigned short Ws[128*32];   // 8 KB

  // ---- XCD-chunked bijective blockIdx swizzle (m204 formula) ----
  const int gx = gridDim.x;
  const int nwg = gx * gridDim.y;
  const int orig = blockIdx.y * gx + blockIdx.x;
  const int q = nwg >> 3, r = nwg & 7;
  const int xcd = orig & 7, idx = orig >> 3;
  const int wg = (xcd < r ? xcd*(q+1) : r*(q+1) + (xcd-r)*q) + idx;
  const int bx = wg % gx, by = wg / gx;

  const int tid  = threadIdx.x;
  const int row0 = by * 128, col0 = bx * 128;
  const int lane = tid & 63;
  const int m16  = lane & 15, quad = lane >> 4;
  const int wv   = tid >> 6;
  const int wm   = (wv & 1) * 64, wn = (wv >> 1) * 64;

  // staging: wave w, lane l -> LDS row w*16 + (l>>2), k-slot (l&3)*8 shorts.
  const int st_row = wv*16 + (lane >> 2);
  const int st_col = (lane & 3) * 8;
  const bf16* ga = &A[(size_t)(row0 + st_row)*lda + st_col];
  const bf16* gw = &W[(size_t)(col0 + st_row)*ldw + st_col];
  unsigned short* lAlo = &As[wv*512];
  unsigned short* lAhi = &As[2048 + wv*512];
  unsigned short* lWlo = &Ws[wv*512];
  unsigned short* lWhi = &Ws[2048 + wv*512];
  const size_t a64 = (size_t)64 * lda;
  const size_t w64 = (size_t)64 * ldw;

  f32x4 acc[4][4] = {};

  for (int k0 = 0; k0 < K; k0 += 32){
    gld_lds16(ga + k0,       lAlo);
    gld_lds16(ga + k0 + a64, lAhi);
    gld_lds16(gw + k0,       lWlo);
    gld_lds16(gw + k0 + w64, lWhi);
    __syncthreads();   // compiler emits vmcnt(0) drain before barrier

    bf16x8 af[4], wf[4];
    #pragma unroll
    for (int i = 0; i < 4; i++){
      af[i] = *reinterpret_cast<const bf16x8*>(&As[(wm + 16*i + m16)*32 + quad*8]);
      wf[i] = *reinterpret_cast<const bf16x8*>(&Ws[(wn + 16*i + m16)*32 + quad*8]);
    }
    #pragma unroll
    for (int i = 0; i < 4; i++)
      #pragma unroll
      for (int j = 0; j < 4; j++)
        acc[i][j] = __builtin_amdgcn_mfma_f32_16x16x32_bf16(af[i], wf[j], acc[i][j], 0, 0, 0);
    __syncthreads();
  }

  // epilogue: C/D layout col=lane&15, row=quad*4+reg  (m89-verified)
  #pragma unroll
  for (int i = 0; i < 4; i++){
    #pragma unroll
    for (int j = 0; j < 4; j++){
      const int col = col0 + wn + 16*j + m16;
      #pragma unroll
      for (int r2 = 0; r2 < 4; r2++){
        const int row = row0 + wm + 16*i + quad*4 + r2;
        float v = acc[i][j][r2];
        if (FLAGS & 1) v += bias[col];
        if (ACT == 1)  v = 0.5f * v * (1.0f + erff(v * 0.70710678118654752f));
        if (FLAGS & 2) v += res[(size_t)row*ldres + col];
        if (FLAGS & 4) v += dscale[col] * res[(size_t)row*ldres + col];
        const size_t o = (size_t)row*ldc + col;
        if (OF) OF[o] = v;
        if (OB) OB[o] = __float2bfloat16(v);
      }
    }
  }
}

// ---------------------------------------------------------------------------
// fp32 tiled GEMMs for the small ends (embed, out) — proven R12 structure.
// ---------------------------------------------------------------------------
__global__ __launch_bounds__(256) void emb_gemm(
    const float* __restrict__ x, const float* __restrict__ W,
    const float* __restrict__ b)
{
  __shared__ __align__(16) float Asx[16][68];
  __shared__ __align__(16) float Wsx[16][68];
  const int tid = threadIdx.x;
  const int tx = tid & 15, ty = tid >> 4;
  const int row0 = blockIdx.y * 64, col0 = blockIdx.x * 64;
  const int lc = tid & 15, lr = tid >> 4;
  float acc[4][4] = {};
  for (int k0 = 0; k0 < INDIM; k0 += 16){
    #pragma unroll
    for (int i = 0; i < 4; i++){
      Asx[lc][lr + 16*i] = x[(size_t)(row0 + lr + 16*i)*INDIM + k0 + lc];
      Wsx[lc][lr + 16*i] = W[(size_t)(col0 + lr + 16*i)*INDIM + k0 + lc];
    }
    __syncthreads();
    #pragma unroll
    for (int k = 0; k < 16; k++){
      float4 av = *reinterpret_cast<const float4*>(&Asx[k][ty*4]);
      float4 bv = *reinterpret_cast<const float4*>(&Wsx[k][tx*4]);
      float a[4] = {av.x, av.y, av.z, av.w};
      float b2[4] = {bv.x, bv.y, bv.z, bv.w};
      #pragma unroll
      for (int i = 0; i < 4; i++)
        #pragma unroll
        for (int j = 0; j < 4; j++)
          acc[i][j] = fmaf(a[i], b2[j], acc[i][j]);
    }
    __syncthreads();
  }
  #pragma unroll
  for (int i = 0; i < 4; i++){
    const int r = row0 + ty*4 + i;
    #pragma unroll
    for (int j = 0; j < 4; j++){
      const int cn = col0 + tx*4 + j;
      float v = acc[i][j] + b[cn];
      g_h [(size_t)r*HIDD + cn] = v;
      g_hb[(size_t)r*HIDD + cn] = __float2bfloat16(v);
    }
  }
}

__global__ __launch_bounds__(256) void out_gemm(
    const float* __restrict__ W, const float* __restrict__ b,
    float* __restrict__ out)
{
  __shared__ __align__(16) float Asx[16][68];
  __shared__ __align__(16) float Wsx[16][68];
  const int tid = threadIdx.x;
  const int tx = tid & 15, ty = tid >> 4;
  const int row0 = blockIdx.y * 64, col0 = blockIdx.x * 64;
  const int lc = tid & 15, lr = tid >> 4;
  float acc[4][4] = {};
  for (int k0 = 0; k0 < HIDD; k0 += 16){
    #pragma unroll
    for (int i = 0; i < 4; i++){
      Asx[lc][lr + 16*i] = g_h[(size_t)(row0 + lr + 16*i)*HIDD + k0 + lc];
      Wsx[lc][lr + 16*i] = W[(size_t)(col0 + lr + 16*i)*HIDD + k0 + lc];
    }
    __syncthreads();
    #pragma unroll
    for (int k = 0; k < 16; k++){
      float4 av = *reinterpret_cast<const float4*>(&Asx[k][ty*4]);
      float4 bv = *reinterpret_cast<const float4*>(&Wsx[k][tx*4]);
      float a[4] = {av.x, av.y, av.z, av.w};
      float b2[4] = {bv.x, bv.y, bv.z, bv.w};
      #pragma unroll
      for (int i = 0; i < 4; i++)
        #pragma unroll
        for (int j = 0; j < 4; j++)
          acc[i][j] = fmaf(a[i], b2[j], acc[i][j]);
    }
    __syncthreads();
  }
  #pragma unroll
  for (int i = 0; i < 4; i++){
    const int r = row0 + ty*4 + i;
    #pragma unroll
    for (int j = 0; j < 4; j++){
      const int cn = col0 + tx*4 + j;
      out[(size_t)r*OUTD + cn] = acc[i][j] + b[cn];
    }
  }
}

// ---------------------------------------------------------------------------
// lam_s = exp(-exp(nu)) * (cos(exp(th)) + i sin(exp(th)))
// ---------------------------------------------------------------------------
__device__ __forceinline__ void lam_of(const float* __restrict__ nu_log,
                                       const float* __restrict__ th_log,
                                       int s, float& lr, float& li)
{
  float nu  = expf(nu_log[s]);
  float th  = expf(th_log[s]);
  float mag = expf(-nu);
  lr = mag * cosf(th);
  li = mag * sinf(th);
}

// Local inclusive scan over 64-token chunks (fp32); chunk carry out.
__global__ __launch_bounds__(256) void scan_local(
    const float* __restrict__ nu_log, const float* __restrict__ th_log)
{
  const int blk = blockIdx.x;          // chunk 0..511
  const int s   = threadIdx.x;
  float lr, li; lam_of(nu_log, th_log, s, lr, li);
  float ar = 0.f, ai = 0.f;
  size_t base = (size_t)blk * CHUNK * 512 + s;
  for (int t = 0; t < CHUNK; t++){
    float br = g_bu[base + (size_t)t*512];
    float bi = g_bu[base + (size_t)t*512 + 256];
    float nr = fmaf(lr, ar, fmaf(-li, ai, br));
    float ni = fmaf(lr, ai, fmaf( li, ar, bi));
    ar = nr; ai = ni;
    g_bu[base + (size_t)t*512]       = ar;
    g_bu[base + (size_t)t*512 + 256] = ai;
  }
  g_carry[(size_t)blk*512 + s]       = ar;
  g_carry[(size_t)blk*512 + 256 + s] = ai;
}

// Fixup + bf16 shadow emit (all chunks; correction only for c>0).
// NOTE: corrected fp32 values are NOT written back to g_bu — downstream
// consumers read only the bf16 shadow g_bub (the fp32 store was dead traffic,
// ~65 MB/layer).
__global__ __launch_bounds__(256) void scan_fix(
    const float* __restrict__ nu_log, const float* __restrict__ th_log)
{
  const int blk = blockIdx.x;
  const int c   = blk & (NCHUNK - 1);
  const int s   = threadIdx.x;
  float lr, li; lam_of(nu_log, th_log, s, lr, li);
  float cr = 0.f, ci = 0.f;
  if (c > 0){
    float Tr = lr, Ti = li;
    #pragma unroll
    for (int i = 0; i < 6; i++){ float nr = Tr*Tr - Ti*Ti; Ti = 2.f*Tr*Ti; Tr = nr; }
    const int bstart = blk - c;
    for (int j = 0; j < c; j++){
      float er = g_carry[(size_t)(bstart + j)*512 + s];
      float ei = g_carry[(size_t)(bstart + j)*512 + 256 + s];
      float nr = fmaf(Tr, cr, fmaf(-Ti, ci, er));
      float ni = fmaf(Tr, ci, fmaf( Ti, cr, ei));
      cr = nr; ci = ni;
    }
  }
  float pr = lr, pi = li;                    // lam^{t+1}
  size_t base = (size_t)blk * CHUNK * 512 + s;
  for (int t = 0; t < CHUNK; t++){
    size_t o = base + (size_t)t*512;
    float vr = g_bu[o], vi = g_bu[o + 256];
    if (c > 0){
      vr += pr*cr - pi*ci;
      vi += pr*ci + pi*cr;
      float nr = pr*lr - pi*li;
      pi = pr*li + pi*lr; pr = nr;
    }
    g_bub[o]       = __float2bfloat16(vr);
    g_bub[o + 256] = __float2bfloat16(vi);
  }
}

// Pack B_norm -> bf16 (512 x 256): re rows 0-255, im rows 256-511
__global__ __launch_bounds__(256) void pack_B(
    const float* __restrict__ Bre, const float* __restrict__ Bim,
    const float* __restrict__ gl)
{
  int idx = blockIdx.x * 256 + threadIdx.x;      // 0..65535
  int s = idx >> 8;
  float g = expf(gl[s]);
  g_Bnb[idx]         = __float2bfloat16(Bre[idx] * g);
  g_Bnb[65536 + idx] = __float2bfloat16(Bim[idx] * g);
}

// Pack Cw -> bf16 (256 x 512): [Cre | -Cim]
__global__ __launch_bounds__(256) void pack_C(
    const float* __restrict__ Cre, const float* __restrict__ Cim)
{
  int idx = blockIdx.x * 256 + threadIdx.x;      // 0..65535
  int h = idx >> 8, s = idx & 255;
  g_Cwb[(size_t)h*512 + s]       = __float2bfloat16( Cre[idx]);
  g_Cwb[(size_t)h*512 + 256 + s] = __float2bfloat16(-Cim[idx]);
}

// Straight fp32 -> bf16 weight convert into selected buffer
__global__ __launch_bounds__(256) void conv_bf16(
    const float* __restrict__ src, int dstSel, int n)
{
  int i = blockIdx.x * 256 + threadIdx.x;
  if (i < n) bufb(dstSel)[i] = __float2bfloat16(src[i]);
}

// ---------------------------------------------------------------------------
extern "C" void kernel_launch(void* const* d_in, const int* in_sizes, int n_in,
                              void* d_out, int out_size, void* d_ws, size_t ws_size,
                              hipStream_t stream)
{
  (void)d_ws; (void)ws_size; (void)out_size; (void)n_in; (void)in_sizes;
  const float* x      = (const float*)d_in[0];
  const float* emb_W  = (const float*)d_in[1];
  const float* emb_b  = (const float*)d_in[2];
  const float* nu_log = (const float*)d_in[3];
  const float* th_log = (const float*)d_in[4];
  const float* ga_log = (const float*)d_in[5];
  const float* B_re   = (const float*)d_in[6];
  const float* B_im   = (const float*)d_in[7];
  const float* C_re   = (const float*)d_in[8];
  const float* C_im   = (const float*)d_in[9];
  const float* Dv     = (const float*)d_in[10];
  const float* Wh     = (const float*)d_in[11];
  const float* bh     = (const float*)d_in[12];
  const float* Wo     = (const float*)d_in[13];
  const float* bo     = (const float*)d_in[14];
  const float* out_W  = (const float*)d_in[15];
  const float* out_b  = (const float*)d_in[16];

  const dim3 blk(256);

  // embed: h = x @ emb_W^T + emb_b  (fp32 GEMM + bf16 shadow)
  emb_gemm<<<dim3(HIDD/64, M_TOK/64), blk, 0, stream>>>(x, emb_W, emb_b);

  for (int l = 0; l < NLAYERS; l++){
    pack_B<<<dim3(256), blk, 0, stream>>>(B_re + (size_t)l*65536,
                                          B_im + (size_t)l*65536,
                                          ga_log + l*STATE_D);
    pack_C<<<dim3(256), blk, 0, stream>>>(C_re + (size_t)l*65536,
                                          C_im + (size_t)l*65536);
    conv_bf16<<<dim3(1024), blk, 0, stream>>>(Wh + (size_t)l*262144, SB_WHB, 262144);
    conv_bf16<<<dim3(1024), blk, 0, stream>>>(Wo + (size_t)l*262144, SB_WOB, 262144);

    // Bu = h @ Bn^T   (32768 x 512 x 256) -> g_bu fp32
    mfma_gemm<0, 0><<<dim3(4, M_TOK/128), blk, 0, stream>>>(
        SB_HB, HIDD, SB_BNB, HIDD, SF_BU, -1, 512,
        nullptr, -1, 0, nullptr, HIDD);

    // chunked scan (fp32) + bf16 shadow
    scan_local<<<dim3(M_TOK/CHUNK), blk, 0, stream>>>(nu_log + l*STATE_D, th_log + l*STATE_D);
    scan_fix  <<<dim3(M_TOK/CHUNK), blk, 0, stream>>>(nu_log + l*STATE_D, th_log + l*STATE_D);

    // y = states @ Cw^T + D*h   (32768 x 256 x 512) -> g_y + g_yb
    mfma_gemm<0, 4><<<dim3(2, M_TOK/128), blk, 0, stream>>>(
        SB_BUB, 512, SB_CWB, 512, SF_Y, SB_YB, HIDD,
        nullptr, SF_H, HIDD, Dv + l*HIDD, 512);

    // z = gelu(y @ Wh^T + bh)   (32768 x 1024 x 256) -> g_zb only
    mfma_gemm<1, 1><<<dim3(8, M_TOK/128), blk, 0, stream>>>(
        SB_YB, HIDD, SB_WHB, STATE_D, -1, SB_ZB, MLPD,
        bh + l*MLPD, -1, 0, nullptr, STATE_D);

    // h = z @ Wo^T + bo + y     (32768 x 256 x 1024) -> g_h + g_hb
    mfma_gemm<0, 3><<<dim3(2, M_TOK/128), blk, 0, stream>>>(
        SB_ZB, MLPD, SB_WOB, MLPD, SF_H, SB_HB, HIDD,
        bo + l*HIDD, SF_Y, HIDD, nullptr, MLPD);
  }

  // out = h @ out_W^T + out_b  (fp32 GEMM, fp32 store)
  out_gemm<<<dim3(OUTD/64, M_TOK/64), blk, 0, stream>>>(out_W, out_b, (float*)d_out);
}

// Round 2
// 1177.071 us; speedup vs baseline: 1.2304x; 1.0197x over previous
//
#include <hip/hip_runtime.h>
#include <hip/hip_bf16.h>
#include <math.h>

typedef __hip_bfloat16 bf16;
typedef __attribute__((ext_vector_type(8))) short bf16x8;   // 8 bf16 = 4 VGPR
typedef __attribute__((ext_vector_type(4))) float f32x4;    // MFMA acc

#define BATCH   16
#define SEQLEN  2048
#define INDIM   64
#define HIDD    256
#define STATE_D 256
#define MLPD    1024
#define OUTD    128
#define NLAYERS 4
#define M_TOK   (BATCH*SEQLEN)     // 32768 tokens
#define CHUNK   64
#define NCHUNK  (SEQLEN/CHUNK)     // 32 chunks per batch

// ---- fp32 masters (residual chain precision) -------------------------------
__device__ float g_h [(size_t)M_TOK*256];
__device__ float g_y [(size_t)M_TOK*256];
__device__ float g_bu[(size_t)M_TOK*512];
__device__ float g_carry[512*512];
// ---- bf16 shadows / packed weights (MFMA operands) -------------------------
__device__ bf16  g_hb [(size_t)M_TOK*256];
__device__ bf16  g_yb [(size_t)M_TOK*256];
__device__ bf16  g_bub[(size_t)M_TOK*512];
__device__ bf16  g_zb [(size_t)M_TOK*1024];
__device__ bf16  g_Bnb[512*256];    // B_norm: rows 0-255 re, 256-511 im
__device__ bf16  g_Cwb[256*512];    // [Cre | -Cim]
__device__ bf16  g_Whb[1024*256];   // layer-local Wh
__device__ bf16  g_Wob[256*1024];   // layer-local Wo

#define SF_H  0
#define SF_Y  1
#define SF_BU 2
#define SB_HB  0
#define SB_YB  1
#define SB_BUB 2
#define SB_ZB  3
#define SB_BNB 4
#define SB_CWB 5
#define SB_WHB 6
#define SB_WOB 7

__device__ __forceinline__ float* buff(int sel){
  switch(sel){ case SF_H: return g_h; case SF_Y: return g_y; default: return g_bu; }
}
__device__ __forceinline__ bf16* bufb(int sel){
  switch(sel){
    case SB_HB:  return g_hb;  case SB_YB:  return g_yb;
    case SB_BUB: return g_bub; case SB_ZB:  return g_zb;
    case SB_BNB: return g_Bnb; case SB_CWB: return g_Cwb;
    case SB_WHB: return g_Whb; default:     return g_Wob; }
}

// async global->LDS, 16B per lane. LDS dest is wave-uniform base + lane*16.
__device__ __forceinline__ void gld_lds16(const void* g, void* l){
  __builtin_amdgcn_global_load_lds(
      (const __attribute__((address_space(1))) unsigned int*)g,
      (__attribute__((address_space(3))) unsigned int*)l, 16, 0, 0);
}

// ---------------------------------------------------------------------------
// MFMA GEMM: C[M,N] = act(A @ W^T + bias) (+res / +dscale*res)
// A: bf16 [M,K] lda;  W: bf16 [N,K] ldw.  128x128 block, 4 waves, BK=32.
// T3-minimum 2-phase double-buffer: issue next K-tile's global_load_lds
// BEFORE reading/MFMA-ing the current tile; single __syncthreads per K-step
// (its vmcnt(0)+lgkmcnt(0) drain lands AFTER ~300-400cy of ds_read+MFMA, so
// load latency is hidden instead of serialized). Bijective XCD-chunked
// blockIdx swizzle for L2 reuse of the A panel across column-blocks.
// FLAGS: 1=bias  2=add res  4=add dscale[n]*res.  ACT: 1=exact GELU.
// ---------------------------------------------------------------------------
template<int ACT, int FLAGS>
__global__ __launch_bounds__(256) void mfma_gemm(
    int aSel, int lda, int wSel, int ldw,
    int oFSel, int oBSel, int ldc,
    const float* __restrict__ bias,
    int rSel, int ldres,
    const float* __restrict__ dscale,
    int K)
{
  const bf16* A = bufb(aSel);
  const bf16* W = bufb(wSel);
  float* OF = (oFSel >= 0) ? buff(oFSel) : nullptr;
  bf16*  OB = (oBSel >= 0) ? bufb(oBSel) : nullptr;
  const float* res = (rSel >= 0) ? buff(rSel) : nullptr;

  __shared__ __align__(16) unsigned short As[2][128*32];   // 2 x 8 KB
  __shared__ __align__(16) unsigned short Ws[2][128*32];   // 2 x 8 KB

  // ---- XCD-chunked bijective blockIdx swizzle (m204 formula) ----
  const int gx = gridDim.x;
  const int nwg = gx * gridDim.y;
  const int orig = blockIdx.y * gx + blockIdx.x;
  const int q = nwg >> 3, r = nwg & 7;
  const int xcd = orig & 7, idx = orig >> 3;
  const int wg = (xcd < r ? xcd*(q+1) : r*(q+1) + (xcd-r)*q) + idx;
  const int bx = wg % gx, by = wg / gx;

  const int tid  = threadIdx.x;
  const int row0 = by * 128, col0 = bx * 128;
  const int lane = tid & 63;
  const int m16  = lane & 15, quad = lane >> 4;
  const int wv   = tid >> 6;
  const int wm   = (wv & 1) * 64, wn = (wv >> 1) * 64;

  // staging: wave w, lane l -> LDS row w*16 + (l>>2), k-slot (l&3)*8 shorts.
  const int st_row = wv*16 + (lane >> 2);
  const int st_col = (lane & 3) * 8;
  const bf16* ga = &A[(size_t)(row0 + st_row)*lda + st_col];
  const bf16* gw = &W[(size_t)(col0 + st_row)*ldw + st_col];
  const size_t a64 = (size_t)64 * lda;
  const size_t w64 = (size_t)64 * ldw;

  auto STAGE = [&](int b, int k0){
    gld_lds16(ga + k0,       &As[b][wv*512]);
    gld_lds16(ga + k0 + a64, &As[b][2048 + wv*512]);
    gld_lds16(gw + k0,       &Ws[b][wv*512]);
    gld_lds16(gw + k0 + w64, &Ws[b][2048 + wv*512]);
  };

  f32x4 acc[4][4] = {};
  const int nt = K >> 5;

  STAGE(0, 0);
  __syncthreads();                       // tile 0 resident

  for (int t = 0; t < nt; ++t){
    const int cur = t & 1;
    if (t + 1 < nt) STAGE(cur ^ 1, (t + 1) << 5);   // async, in flight during MFMA

    bf16x8 af[4], wf[4];
    #pragma unroll
    for (int i = 0; i < 4; i++){
      af[i] = *reinterpret_cast<const bf16x8*>(&As[cur][(wm + 16*i + m16)*32 + quad*8]);
      wf[i] = *reinterpret_cast<const bf16x8*>(&Ws[cur][(wn + 16*i + m16)*32 + quad*8]);
    }
    #pragma unroll
    for (int i = 0; i < 4; i++)
      #pragma unroll
      for (int j = 0; j < 4; j++)
        acc[i][j] = __builtin_amdgcn_mfma_f32_16x16x32_bf16(af[i], wf[j], acc[i][j], 0, 0, 0);

    __syncthreads();   // drains next-tile loads (partially overlapped) + guards buf reuse
  }

  // epilogue: C/D layout col=lane&15, row=quad*4+reg  (m89-verified)
  #pragma unroll
  for (int i = 0; i < 4; i++){
    #pragma unroll
    for (int j = 0; j < 4; j++){
      const int col = col0 + wn + 16*j + m16;
      #pragma unroll
      for (int r2 = 0; r2 < 4; r2++){
        const int row = row0 + wm + 16*i + quad*4 + r2;
        float v = acc[i][j][r2];
        if (FLAGS & 1) v += bias[col];
        if (ACT == 1)  v = 0.5f * v * (1.0f + erff(v * 0.70710678118654752f));
        if (FLAGS & 2) v += res[(size_t)row*ldres + col];
        if (FLAGS & 4) v += dscale[col] * res[(size_t)row*ldres + col];
        const size_t o = (size_t)row*ldc + col;
        if (OF) OF[o] = v;
        if (OB) OB[o] = __float2bfloat16(v);
      }
    }
  }
}

// ---------------------------------------------------------------------------
// fp32 tiled GEMMs for the small ends (embed, out) — proven R12 structure.
// ---------------------------------------------------------------------------
__global__ __launch_bounds__(256) void emb_gemm(
    const float* __restrict__ x, const float* __restrict__ W,
    const float* __restrict__ b)
{
  __shared__ __align__(16) float Asx[16][68];
  __shared__ __align__(16) float Wsx[16][68];
  const int tid = threadIdx.x;
  const int tx = tid & 15, ty = tid >> 4;
  const int row0 = blockIdx.y * 64, col0 = blockIdx.x * 64;
  const int lc = tid & 15, lr = tid >> 4;
  float acc[4][4] = {};
  for (int k0 = 0; k0 < INDIM; k0 += 16){
    #pragma unroll
    for (int i = 0; i < 4; i++){
      Asx[lc][lr + 16*i] = x[(size_t)(row0 + lr + 16*i)*INDIM + k0 + lc];
      Wsx[lc][lr + 16*i] = W[(size_t)(col0 + lr + 16*i)*INDIM + k0 + lc];
    }
    __syncthreads();
    #pragma unroll
    for (int k = 0; k < 16; k++){
      float4 av = *reinterpret_cast<const float4*>(&Asx[k][ty*4]);
      float4 bv = *reinterpret_cast<const float4*>(&Wsx[k][tx*4]);
      float a[4] = {av.x, av.y, av.z, av.w};
      float b2[4] = {bv.x, bv.y, bv.z, bv.w};
      #pragma unroll
      for (int i = 0; i < 4; i++)
        #pragma unroll
        for (int j = 0; j < 4; j++)
          acc[i][j] = fmaf(a[i], b2[j], acc[i][j]);
    }
    __syncthreads();
  }
  #pragma unroll
  for (int i = 0; i < 4; i++){
    const int r = row0 + ty*4 + i;
    #pragma unroll
    for (int j = 0; j < 4; j++){
      const int cn = col0 + tx*4 + j;
      float v = acc[i][j] + b[cn];
      g_h [(size_t)r*HIDD + cn] = v;
      g_hb[(size_t)r*HIDD + cn] = __float2bfloat16(v);
    }
  }
}

__global__ __launch_bounds__(256) void out_gemm(
    const float* __restrict__ W, const float* __restrict__ b,
    float* __restrict__ out)
{
  __shared__ __align__(16) float Asx[16][68];
  __shared__ __align__(16) float Wsx[16][68];
  const int tid = threadIdx.x;
  const int tx = tid & 15, ty = tid >> 4;
  const int row0 = blockIdx.y * 64, col0 = blockIdx.x * 64;
  const int lc = tid & 15, lr = tid >> 4;
  float acc[4][4] = {};
  for (int k0 = 0; k0 < HIDD; k0 += 16){
    #pragma unroll
    for (int i = 0; i < 4; i++){
      Asx[lc][lr + 16*i] = g_h[(size_t)(row0 + lr + 16*i)*HIDD + k0 + lc];
      Wsx[lc][lr + 16*i] = W[(size_t)(col0 + lr + 16*i)*HIDD + k0 + lc];
    }
    __syncthreads();
    #pragma unroll
    for (int k = 0; k < 16; k++){
      float4 av = *reinterpret_cast<const float4*>(&Asx[k][ty*4]);
      float4 bv = *reinterpret_cast<const float4*>(&Wsx[k][tx*4]);
      float a[4] = {av.x, av.y, av.z, av.w};
      float b2[4] = {bv.x, bv.y, bv.z, bv.w};
      #pragma unroll
      for (int i = 0; i < 4; i++)
        #pragma unroll
        for (int j = 0; j < 4; j++)
          acc[i][j] = fmaf(a[i], b2[j], acc[i][j]);
    }
    __syncthreads();
  }
  #pragma unroll
  for (int i = 0; i < 4; i++){
    const int r = row0 + ty*4 + i;
    #pragma unroll
    for (int j = 0; j < 4; j++){
      const int cn = col0 + tx*4 + j;
      out[(size_t)r*OUTD + cn] = acc[i][j] + b[cn];
    }
  }
}

// ---------------------------------------------------------------------------
// lam_s = exp(-exp(nu)) * (cos(exp(th)) + i sin(exp(th)))
// ---------------------------------------------------------------------------
__device__ __forceinline__ void lam_of(const float* __restrict__ nu_log,
                                       const float* __restrict__ th_log,
                                       int s, float& lr, float& li)
{
  float nu  = expf(nu_log[s]);
  float th  = expf(th_log[s]);
  float mag = expf(-nu);
  lr = mag * cosf(th);
  li = mag * sinf(th);
}

// Carry-only local scan over 64-token chunks (fp32). No g_bu write-back:
// scan_fix recomputes the local scan seeded with the chunk prefix, which is
// numerically the same recurrence. Saves 67 MB of HBM writes per layer.
__global__ __launch_bounds__(256) void scan_local(
    const float* __restrict__ nu_log, const float* __restrict__ th_log)
{
  const int blk = blockIdx.x;          // chunk 0..511
  const int s   = threadIdx.x;
  float lr, li; lam_of(nu_log, th_log, s, lr, li);
  float ar = 0.f, ai = 0.f;
  size_t base = (size_t)blk * CHUNK * 512 + s;
  for (int t = 0; t < CHUNK; t++){
    float br = g_bu[base + (size_t)t*512];
    float bi = g_bu[base + (size_t)t*512 + 256];
    float nr = fmaf(lr, ar, fmaf(-li, ai, br));
    float ni = fmaf(lr, ai, fmaf( li, ar, bi));
    ar = nr; ai = ni;
  }
  g_carry[(size_t)blk*512 + s]       = ar;
  g_carry[(size_t)blk*512 + 256 + s] = ai;
}

// Prefix accumulate + full local re-scan seeded with prefix; bf16 emit only.
__global__ __launch_bounds__(256) void scan_fix(
    const float* __restrict__ nu_log, const float* __restrict__ th_log)
{
  const int blk = blockIdx.x;
  const int c   = blk & (NCHUNK - 1);
  const int s   = threadIdx.x;
  float lr, li; lam_of(nu_log, th_log, s, lr, li);
  float cr = 0.f, ci = 0.f;
  if (c > 0){
    float Tr = lr, Ti = li;
    #pragma unroll
    for (int i = 0; i < 6; i++){ float nr = Tr*Tr - Ti*Ti; Ti = 2.f*Tr*Ti; Tr = nr; }
    const int bstart = blk - c;
    for (int j = 0; j < c; j++){
      float er = g_carry[(size_t)(bstart + j)*512 + s];
      float ei = g_carry[(size_t)(bstart + j)*512 + 256 + s];
      float nr = fmaf(Tr, cr, fmaf(-Ti, ci, er));
      float ni = fmaf(Tr, ci, fmaf( Ti, cr, ei));
      cr = nr; ci = ni;
    }
  }
  // inclusive scan with incoming state (cr,ci): state_t = lam^{t+1}*prefix + local_t
  float ar = cr, ai = ci;
  size_t base = (size_t)blk * CHUNK * 512 + s;
  for (int t = 0; t < CHUNK; t++){
    size_t o = base + (size_t)t*512;
    float br = g_bu[o], bi = g_bu[o + 256];
    float nr = fmaf(lr, ar, fmaf(-li, ai, br));
    float ni = fmaf(lr, ai, fmaf( li, ar, bi));
    ar = nr; ai = ni;
    g_bub[o]       = __float2bfloat16(ar);
    g_bub[o + 256] = __float2bfloat16(ai);
  }
}

// Pack B_norm -> bf16 (512 x 256): re rows 0-255, im rows 256-511
__global__ __launch_bounds__(256) void pack_B(
    const float* __restrict__ Bre, const float* __restrict__ Bim,
    const float* __restrict__ gl)
{
  int idx = blockIdx.x * 256 + threadIdx.x;      // 0..65535
  int s = idx >> 8;
  float g = expf(gl[s]);
  g_Bnb[idx]         = __float2bfloat16(Bre[idx] * g);
  g_Bnb[65536 + idx] = __float2bfloat16(Bim[idx] * g);
}

// Pack Cw -> bf16 (256 x 512): [Cre | -Cim]
__global__ __launch_bounds__(256) void pack_C(
    const float* __restrict__ Cre, const float* __restrict__ Cim)
{
  int idx = blockIdx.x * 256 + threadIdx.x;      // 0..65535
  int h = idx >> 8, s = idx & 255;
  g_Cwb[(size_t)h*512 + s]       = __float2bfloat16( Cre[idx]);
  g_Cwb[(size_t)h*512 + 256 + s] = __float2bfloat16(-Cim[idx]);
}

// Straight fp32 -> bf16 weight convert into selected buffer
__global__ __launch_bounds__(256) void conv_bf16(
    const float* __restrict__ src, int dstSel, int n)
{
  int i = blockIdx.x * 256 + threadIdx.x;
  if (i < n) bufb(dstSel)[i] = __float2bfloat16(src[i]);
}

// ---------------------------------------------------------------------------
extern "C" void kernel_launch(void* const* d_in, const int* in_sizes, int n_in,
                              void* d_out, int out_size, void* d_ws, size_t ws_size,
                              hipStream_t stream)
{
  (void)d_ws; (void)ws_size; (void)out_size; (void)n_in; (void)in_sizes;
  const float* x      = (const float*)d_in[0];
  const float* emb_W  = (const float*)d_in[1];
  const float* emb_b  = (const float*)d_in[2];
  const float* nu_log = (const float*)d_in[3];
  const float* th_log = (const float*)d_in[4];
  const float* ga_log = (const float*)d_in[5];
  const float* B_re   = (const float*)d_in[6];
  const float* B_im   = (const float*)d_in[7];
  const float* C_re   = (const float*)d_in[8];
  const float* C_im   = (const float*)d_in[9];
  const float* Dv     = (const float*)d_in[10];
  const float* Wh     = (const float*)d_in[11];
  const float* bh     = (const float*)d_in[12];
  const float* Wo     = (const float*)d_in[13];
  const float* bo     = (const float*)d_in[14];
  const float* out_W  = (const float*)d_in[15];
  const float* out_b  = (const float*)d_in[16];

  const dim3 blk(256);

  // embed: h = x @ emb_W^T + emb_b  (fp32 GEMM + bf16 shadow)
  emb_gemm<<<dim3(HIDD/64, M_TOK/64), blk, 0, stream>>>(x, emb_W, emb_b);

  for (int l = 0; l < NLAYERS; l++){
    pack_B<<<dim3(256), blk, 0, stream>>>(B_re + (size_t)l*65536,
                                          B_im + (size_t)l*65536,
                                          ga_log + l*STATE_D);
    pack_C<<<dim3(256), blk, 0, stream>>>(C_re + (size_t)l*65536,
                                          C_im + (size_t)l*65536);
    conv_bf16<<<dim3(1024), blk, 0, stream>>>(Wh + (size_t)l*262144, SB_WHB, 262144);
    conv_bf16<<<dim3(1024), blk, 0, stream>>>(Wo + (size_t)l*262144, SB_WOB, 262144);

    // Bu = h @ Bn^T   (32768 x 512 x 256) -> g_bu fp32
    mfma_gemm<0, 0><<<dim3(4, M_TOK/128), blk, 0, stream>>>(
        SB_HB, HIDD, SB_BNB, HIDD, SF_BU, -1, 512,
        nullptr, -1, 0, nullptr, HIDD);

    // chunked scan (fp32) + bf16 shadow
    scan_local<<<dim3(M_TOK/CHUNK), blk, 0, stream>>>(nu_log + l*STATE_D, th_log + l*STATE_D);
    scan_fix  <<<dim3(M_TOK/CHUNK), blk, 0, stream>>>(nu_log + l*STATE_D, th_log + l*STATE_D);

    // y = states @ Cw^T + D*h   (32768 x 256 x 512) -> g_y + g_yb
    mfma_gemm<0, 4><<<dim3(2, M_TOK/128), blk, 0, stream>>>(
        SB_BUB, 512, SB_CWB, 512, SF_Y, SB_YB, HIDD,
        nullptr, SF_H, HIDD, Dv + l*HIDD, 512);

    // z = gelu(y @ Wh^T + bh)   (32768 x 1024 x 256) -> g_zb only
    mfma_gemm<1, 1><<<dim3(8, M_TOK/128), blk, 0, stream>>>(
        SB_YB, HIDD, SB_WHB, STATE_D, -1, SB_ZB, MLPD,
        bh + l*MLPD, -1, 0, nullptr, STATE_D);

    // h = z @ Wo^T + bo + y     (32768 x 256 x 1024) -> g_h + g_hb
    mfma_gemm<0, 3><<<dim3(2, M_TOK/128), blk, 0, stream>>>(
        SB_ZB, MLPD, SB_WOB, MLPD, SF_H, SB_HB, HIDD,
        bo + l*HIDD, SF_Y, HIDD, nullptr, MLPD);
  }

  // out = h @ out_W^T + out_b  (fp32 GEMM, fp32 store)
  out_gemm<<<dim3(OUTD/64, M_TOK/64), blk, 0, stream>>>(out_W, out_b, (float*)d_out);
}

// Round 3
// 1125.221 us; speedup vs baseline: 1.2871x; 1.0461x over previous
//
#include <hip/hip_runtime.h>
#include <hip/hip_bf16.h>
#include <math.h>

typedef __hip_bfloat16 bf16;
typedef __attribute__((ext_vector_type(8))) short bf16x8;   // 8 bf16 = 4 VGPR
typedef __attribute__((ext_vector_type(4))) float f32x4;    // MFMA acc

#define BATCH   16
#define SEQLEN  2048
#define INDIM   64
#define HIDD    256
#define STATE_D 256
#define MLPD    1024
#define OUTD    128
#define NLAYERS 4
#define M_TOK   (BATCH*SEQLEN)     // 32768 tokens
#define CHUNK   64
#define NCHUNK  (SEQLEN/CHUNK)     // 32 chunks per batch

// ---- fp32 masters (residual chain precision) -------------------------------
__device__ float g_h [(size_t)M_TOK*256];
__device__ float g_y [(size_t)M_TOK*256];
__device__ float g_bu[(size_t)M_TOK*512];
__device__ float g_carry[512*512];
// ---- bf16 shadows / packed weights (MFMA operands) -------------------------
__device__ bf16  g_hb [(size_t)M_TOK*256];
__device__ bf16  g_yb [(size_t)M_TOK*256];
__device__ bf16  g_bub[(size_t)M_TOK*512];
__device__ bf16  g_zb [(size_t)M_TOK*1024];
// per-layer packed weights (hoisted out of the layer loop)
__device__ bf16  g_Bnb[NLAYERS*512*256];    // B_norm: rows 0-255 re, 256-511 im
__device__ bf16  g_Cwb[NLAYERS*256*512];    // [Cre | -Cim]
__device__ bf16  g_Whb[NLAYERS*1024*256];
__device__ bf16  g_Wob[NLAYERS*256*1024];

#define SF_H  0
#define SF_Y  1
#define SF_BU 2
#define SB_HB  0
#define SB_YB  1
#define SB_BUB 2
#define SB_ZB  3
#define SB_BNB 4
#define SB_CWB 5
#define SB_WHB 6
#define SB_WOB 7

__device__ __forceinline__ float* buff(int sel){
  switch(sel){ case SF_H: return g_h; case SF_Y: return g_y; default: return g_bu; }
}
__device__ __forceinline__ bf16* bufb(int sel){
  switch(sel){
    case SB_HB:  return g_hb;  case SB_YB:  return g_yb;
    case SB_BUB: return g_bub; case SB_ZB:  return g_zb;
    case SB_BNB: return g_Bnb; case SB_CWB: return g_Cwb;
    case SB_WHB: return g_Whb; default:     return g_Wob; }
}

// async global->LDS, 16B per lane. LDS dest is wave-uniform base + lane*16.
__device__ __forceinline__ void gld_lds16(const void* g, void* l){
  __builtin_amdgcn_global_load_lds(
      (const __attribute__((address_space(1))) unsigned int*)g,
      (__attribute__((address_space(3))) unsigned int*)l, 16, 0, 0);
}

// ---------------------------------------------------------------------------
// MFMA GEMM: C[M,N] = act(A @ W^T + bias) (+res / +dscale*res)
// A: bf16 [M,K] lda;  W: bf16 [N,K] ldw (+wOff).  128x128 block, 4 waves, BK=32.
// 3-deep LDS ring buffer (T3/T4): tile t's loads are issued 3 iterations
// before their counted s_waitcnt vmcnt(8) — ~1200cy of cover vs ~900cy HBM
// latency. Raw s_barrier (no implicit vmcnt(0) drain). Buffer-reuse guarded
// by lgkmcnt(0)+barrier before re-staging.
// T2 swizzle (rule #21, linear LDS dest + swizzled GLOBAL source): LDS slot
// (l&3) of row r holds k-group (l&3)^((r>>1)&3); reader uses quad^((r>>1)&3).
// Spreads the 64B-row-stride ds_read_b128 over 8 bank-groups (2-way = free).
// FLAGS: 1=bias  2=add res  4=add dscale[n]*res.  ACT: 1=exact GELU.
// ---------------------------------------------------------------------------
template<int ACT, int FLAGS>
__global__ __launch_bounds__(256, 2) void mfma_gemm(
    int aSel, int lda, int wSel, int wOff, int ldw,
    int oFSel, int oBSel, int ldc,
    const float* __restrict__ bias,
    int rSel, int ldres,
    const float* __restrict__ dscale,
    int K)
{
  const bf16* A = bufb(aSel);
  const bf16* W = bufb(wSel) + wOff;
  float* OF = (oFSel >= 0) ? buff(oFSel) : nullptr;
  bf16*  OB = (oBSel >= 0) ? bufb(oBSel) : nullptr;
  const float* res = (rSel >= 0) ? buff(rSel) : nullptr;

  __shared__ __align__(16) unsigned short As[3*128*32];   // 3 x 8 KB
  __shared__ __align__(16) unsigned short Ws[3*128*32];   // 3 x 8 KB

  // ---- XCD-chunked bijective blockIdx swizzle (m204 formula) ----
  const int gx = gridDim.x;
  const int nwg = gx * gridDim.y;
  const int orig = blockIdx.y * gx + blockIdx.x;
  const int q = nwg >> 3, r = nwg & 7;
  const int xcd = orig & 7, idx = orig >> 3;
  const int wg = (xcd < r ? xcd*(q+1) : r*(q+1) + (xcd-r)*q) + idx;
  const int bx = wg % gx, by = wg / gx;

  const int tid  = threadIdx.x;
  const int row0 = by * 128, col0 = bx * 128;
  const int lane = tid & 63;
  const int m16  = lane & 15, quad = lane >> 4;
  const int wv   = tid >> 6;
  const int wm   = (wv & 1) * 64, wn = (wv >> 1) * 64;

  // staging: wave w, lane l -> LDS row w*16 + (l>>2), slot (l&3).
  // Source k-group is XOR-swizzled by row (same f for row and row+64).
  const int rlo = wv*16 + (lane >> 2);
  const int sg  = ((lane & 3) ^ ((rlo >> 1) & 3)) * 8;    // shorts
  const bf16* ga = &A[(size_t)(row0 + rlo)*lda + sg];
  const bf16* gw = &W[(size_t)(col0 + rlo)*ldw + sg];
  const size_t a64 = (size_t)64 * lda;
  const size_t w64 = (size_t)64 * ldw;

  auto STAGE = [&](int bb, int k0){
    unsigned short* Ab = As + bb*4096;
    unsigned short* Wb = Ws + bb*4096;
    gld_lds16(ga + k0,       Ab + wv*512);
    gld_lds16(ga + k0 + a64, Ab + 2048 + wv*512);
    gld_lds16(gw + k0,       Wb + wv*512);
    gld_lds16(gw + k0 + w64, Wb + 2048 + wv*512);
  };

  f32x4 acc[4][4] = {};
  const int nt = K >> 5;          // >= 8 for all our shapes

  STAGE(0, 0); STAGE(1, 32); STAGE(2, 64);   // 12 loads in flight

  int b = 0;
  for (int t = 0; t < nt; ++t){
    // tile t resident when <= 4*younger loads outstanding
    const int younger = nt - 1 - t;
    if (younger >= 2)      asm volatile("s_waitcnt vmcnt(8)" ::: "memory");
    else if (younger == 1) asm volatile("s_waitcnt vmcnt(4)" ::: "memory");
    else                   asm volatile("s_waitcnt vmcnt(0)" ::: "memory");
    __builtin_amdgcn_s_barrier();            // all waves' portions resident

    const unsigned short* Ab = As + b*4096;
    const unsigned short* Wb = Ws + b*4096;
    bf16x8 af[4], wf[4];
    #pragma unroll
    for (int i = 0; i < 4; i++){
      const int rA = wm + 16*i + m16;
      const int rW = wn + 16*i + m16;
      af[i] = *reinterpret_cast<const bf16x8*>(&Ab[rA*32 + ((quad ^ ((rA >> 1) & 3)) << 3)]);
      wf[i] = *reinterpret_cast<const bf16x8*>(&Wb[rW*32 + ((quad ^ ((rW >> 1) & 3)) << 3)]);
    }
    asm volatile("s_waitcnt lgkmcnt(0)" ::: "memory");   // this wave's reads done
    __builtin_amdgcn_sched_barrier(0);                   // rule #18
    __builtin_amdgcn_s_barrier();                        // all waves done with buf b

    if (t + 3 < nt) STAGE(b, (t + 3) << 5);              // refill freed buffer

    __builtin_amdgcn_s_setprio(1);
    #pragma unroll
    for (int i = 0; i < 4; i++)
      #pragma unroll
      for (int j = 0; j < 4; j++)
        acc[i][j] = __builtin_amdgcn_mfma_f32_16x16x32_bf16(af[i], wf[j], acc[i][j], 0, 0, 0);
    __builtin_amdgcn_s_setprio(0);

    b = (b == 2) ? 0 : b + 1;
  }

  // epilogue: C/D layout col=lane&15, row=quad*4+reg  (m89-verified)
  #pragma unroll
  for (int i = 0; i < 4; i++){
    #pragma unroll
    for (int j = 0; j < 4; j++){
      const int col = col0 + wn + 16*j + m16;
      #pragma unroll
      for (int r2 = 0; r2 < 4; r2++){
        const int row = row0 + wm + 16*i + quad*4 + r2;
        float v = acc[i][j][r2];
        if (FLAGS & 1) v += bias[col];
        if (ACT == 1)  v = 0.5f * v * (1.0f + erff(v * 0.70710678118654752f));
        if (FLAGS & 2) v += res[(size_t)row*ldres + col];
        if (FLAGS & 4) v += dscale[col] * res[(size_t)row*ldres + col];
        const size_t o = (size_t)row*ldc + col;
        if (OF) OF[o] = v;
        if (OB) OB[o] = __float2bfloat16(v);
      }
    }
  }
}

// ---------------------------------------------------------------------------
// fp32 tiled GEMMs for the small ends (embed, out) — proven R12 structure.
// ---------------------------------------------------------------------------
__global__ __launch_bounds__(256) void emb_gemm(
    const float* __restrict__ x, const float* __restrict__ W,
    const float* __restrict__ b)
{
  __shared__ __align__(16) float Asx[16][68];
  __shared__ __align__(16) float Wsx[16][68];
  const int tid = threadIdx.x;
  const int tx = tid & 15, ty = tid >> 4;
  const int row0 = blockIdx.y * 64, col0 = blockIdx.x * 64;
  const int lc = tid & 15, lr = tid >> 4;
  float acc[4][4] = {};
  for (int k0 = 0; k0 < INDIM; k0 += 16){
    #pragma unroll
    for (int i = 0; i < 4; i++){
      Asx[lc][lr + 16*i] = x[(size_t)(row0 + lr + 16*i)*INDIM + k0 + lc];
      Wsx[lc][lr + 16*i] = W[(size_t)(col0 + lr + 16*i)*INDIM + k0 + lc];
    }
    __syncthreads();
    #pragma unroll
    for (int k = 0; k < 16; k++){
      float4 av = *reinterpret_cast<const float4*>(&Asx[k][ty*4]);
      float4 bv = *reinterpret_cast<const float4*>(&Wsx[k][tx*4]);
      float a[4] = {av.x, av.y, av.z, av.w};
      float b2[4] = {bv.x, bv.y, bv.z, bv.w};
      #pragma unroll
      for (int i = 0; i < 4; i++)
        #pragma unroll
        for (int j = 0; j < 4; j++)
          acc[i][j] = fmaf(a[i], b2[j], acc[i][j]);
    }
    __syncthreads();
  }
  #pragma unroll
  for (int i = 0; i < 4; i++){
    const int r = row0 + ty*4 + i;
    #pragma unroll
    for (int j = 0; j < 4; j++){
      const int cn = col0 + tx*4 + j;
      float v = acc[i][j] + b[cn];
      g_h [(size_t)r*HIDD + cn] = v;
      g_hb[(size_t)r*HIDD + cn] = __float2bfloat16(v);
    }
  }
}

__global__ __launch_bounds__(256) void out_gemm(
    const float* __restrict__ W, const float* __restrict__ b,
    float* __restrict__ out)
{
  __shared__ __align__(16) float Asx[16][68];
  __shared__ __align__(16) float Wsx[16][68];
  const int tid = threadIdx.x;
  const int tx = tid & 15, ty = tid >> 4;
  const int row0 = blockIdx.y * 64, col0 = blockIdx.x * 64;
  const int lc = tid & 15, lr = tid >> 4;
  float acc[4][4] = {};
  for (int k0 = 0; k0 < HIDD; k0 += 16){
    #pragma unroll
    for (int i = 0; i < 4; i++){
      Asx[lc][lr + 16*i] = g_h[(size_t)(row0 + lr + 16*i)*HIDD + k0 + lc];
      Wsx[lc][lr + 16*i] = W[(size_t)(col0 + lr + 16*i)*HIDD + k0 + lc];
    }
    __syncthreads();
    #pragma unroll
    for (int k = 0; k < 16; k++){
      float4 av = *reinterpret_cast<const float4*>(&Asx[k][ty*4]);
      float4 bv = *reinterpret_cast<const float4*>(&Wsx[k][tx*4]);
      float a[4] = {av.x, av.y, av.z, av.w};
      float b2[4] = {bv.x, bv.y, bv.z, bv.w};
      #pragma unroll
      for (int i = 0; i < 4; i++)
        #pragma unroll
        for (int j = 0; j < 4; j++)
          acc[i][j] = fmaf(a[i], b2[j], acc[i][j]);
    }
    __syncthreads();
  }
  #pragma unroll
  for (int i = 0; i < 4; i++){
    const int r = row0 + ty*4 + i;
    #pragma unroll
    for (int j = 0; j < 4; j++){
      const int cn = col0 + tx*4 + j;
      out[(size_t)r*OUTD + cn] = acc[i][j] + b[cn];
    }
  }
}

// ---------------------------------------------------------------------------
// lam_s = exp(-exp(nu)) * (cos(exp(th)) + i sin(exp(th)))
// ---------------------------------------------------------------------------
__device__ __forceinline__ void lam_of(const float* __restrict__ nu_log,
                                       const float* __restrict__ th_log,
                                       int s, float& lr, float& li)
{
  float nu  = expf(nu_log[s]);
  float th  = expf(th_log[s]);
  float mag = expf(-nu);
  lr = mag * cosf(th);
  li = mag * sinf(th);
}

// Carry-only local scan over 64-token chunks (fp32).
__global__ __launch_bounds__(256) void scan_local(
    const float* __restrict__ nu_log, const float* __restrict__ th_log)
{
  const int blk = blockIdx.x;          // chunk 0..511
  const int s   = threadIdx.x;
  float lr, li; lam_of(nu_log, th_log, s, lr, li);
  float ar = 0.f, ai = 0.f;
  size_t base = (size_t)blk * CHUNK * 512 + s;
  for (int t = 0; t < CHUNK; t++){
    float br = g_bu[base + (size_t)t*512];
    float bi = g_bu[base + (size_t)t*512 + 256];
    float nr = fmaf(lr, ar, fmaf(-li, ai, br));
    float ni = fmaf(lr, ai, fmaf( li, ar, bi));
    ar = nr; ai = ni;
  }
  g_carry[(size_t)blk*512 + s]       = ar;
  g_carry[(size_t)blk*512 + 256 + s] = ai;
}

// Prefix accumulate + full local re-scan seeded with prefix; bf16 emit only.
__global__ __launch_bounds__(256) void scan_fix(
    const float* __restrict__ nu_log, const float* __restrict__ th_log)
{
  const int blk = blockIdx.x;
  const int c   = blk & (NCHUNK - 1);
  const int s   = threadIdx.x;
  float lr, li; lam_of(nu_log, th_log, s, lr, li);
  float cr = 0.f, ci = 0.f;
  if (c > 0){
    float Tr = lr, Ti = li;
    #pragma unroll
    for (int i = 0; i < 6; i++){ float nr = Tr*Tr - Ti*Ti; Ti = 2.f*Tr*Ti; Tr = nr; }
    const int bstart = blk - c;
    for (int j = 0; j < c; j++){
      float er = g_carry[(size_t)(bstart + j)*512 + s];
      float ei = g_carry[(size_t)(bstart + j)*512 + 256 + s];
      float nr = fmaf(Tr, cr, fmaf(-Ti, ci, er));
      float ni = fmaf(Tr, ci, fmaf( Ti, cr, ei));
      cr = nr; ci = ni;
    }
  }
  // inclusive scan with incoming state (cr,ci)
  float ar = cr, ai = ci;
  size_t base = (size_t)blk * CHUNK * 512 + s;
  for (int t = 0; t < CHUNK; t++){
    size_t o = base + (size_t)t*512;
    float br = g_bu[o], bi = g_bu[o + 256];
    float nr = fmaf(lr, ar, fmaf(-li, ai, br));
    float ni = fmaf(lr, ai, fmaf( li, ar, bi));
    ar = nr; ai = ni;
    g_bub[o]       = __float2bfloat16(ar);
    g_bub[o + 256] = __float2bfloat16(ai);
  }
}

// Pack B_norm for ALL layers -> bf16 (per layer 512 x 256)
__global__ __launch_bounds__(256) void pack_B(
    const float* __restrict__ Bre, const float* __restrict__ Bim,
    const float* __restrict__ gl)
{
  int idx = blockIdx.x * 256 + threadIdx.x;      // 0..NLAYERS*65536-1
  int l = idx >> 16, within = idx & 65535;
  int s = within >> 8;
  float g = expf(gl[l*STATE_D + s]);
  g_Bnb[(size_t)l*131072 + within]         = __float2bfloat16(Bre[idx] * g);
  g_Bnb[(size_t)l*131072 + 65536 + within] = __float2bfloat16(Bim[idx] * g);
}

// Pack Cw for ALL layers -> bf16 (per layer 256 x 512): [Cre | -Cim]
__global__ __launch_bounds__(256) void pack_C(
    const float* __restrict__ Cre, const float* __restrict__ Cim)
{
  int idx = blockIdx.x * 256 + threadIdx.x;      // 0..NLAYERS*65536-1
  int l = idx >> 16, within = idx & 65535;
  int h = within >> 8, s = within & 255;
  g_Cwb[(size_t)l*131072 + (size_t)h*512 + s]       = __float2bfloat16( Cre[idx]);
  g_Cwb[(size_t)l*131072 + (size_t)h*512 + 256 + s] = __float2bfloat16(-Cim[idx]);
}

// Straight fp32 -> bf16 weight convert into selected buffer
__global__ __launch_bounds__(256) void conv_bf16(
    const float* __restrict__ src, int dstSel, int n)
{
  int i = blockIdx.x * 256 + threadIdx.x;
  if (i < n) bufb(dstSel)[i] = __float2bfloat16(src[i]);
}

// ---------------------------------------------------------------------------
extern "C" void kernel_launch(void* const* d_in, const int* in_sizes, int n_in,
                              void* d_out, int out_size, void* d_ws, size_t ws_size,
                              hipStream_t stream)
{
  (void)d_ws; (void)ws_size; (void)out_size; (void)n_in; (void)in_sizes;
  const float* x      = (const float*)d_in[0];
  const float* emb_W  = (const float*)d_in[1];
  const float* emb_b  = (const float*)d_in[2];
  const float* nu_log = (const float*)d_in[3];
  const float* th_log = (const float*)d_in[4];
  const float* ga_log = (const float*)d_in[5];
  const float* B_re   = (const float*)d_in[6];
  const float* B_im   = (const float*)d_in[7];
  const float* C_re   = (const float*)d_in[8];
  const float* C_im   = (const float*)d_in[9];
  const float* Dv     = (const float*)d_in[10];
  const float* Wh     = (const float*)d_in[11];
  const float* bh     = (const float*)d_in[12];
  const float* Wo     = (const float*)d_in[13];
  const float* bo     = (const float*)d_in[14];
  const float* out_W  = (const float*)d_in[15];
  const float* out_b  = (const float*)d_in[16];

  const dim3 blk(256);

  // ---- all weight packing upfront (independent of activations) ----
  pack_B<<<dim3(NLAYERS*256), blk, 0, stream>>>(B_re, B_im, ga_log);
  pack_C<<<dim3(NLAYERS*256), blk, 0, stream>>>(C_re, C_im);
  conv_bf16<<<dim3(NLAYERS*1024), blk, 0, stream>>>(Wh, SB_WHB, NLAYERS*262144);
  conv_bf16<<<dim3(NLAYERS*1024), blk, 0, stream>>>(Wo, SB_WOB, NLAYERS*262144);

  // embed: h = x @ emb_W^T + emb_b  (fp32 GEMM + bf16 shadow)
  emb_gemm<<<dim3(HIDD/64, M_TOK/64), blk, 0, stream>>>(x, emb_W, emb_b);

  for (int l = 0; l < NLAYERS; l++){
    // Bu = h @ Bn^T   (32768 x 512 x 256) -> g_bu fp32
    mfma_gemm<0, 0><<<dim3(4, M_TOK/128), blk, 0, stream>>>(
        SB_HB, HIDD, SB_BNB, l*131072, HIDD, SF_BU, -1, 512,
        nullptr, -1, 0, nullptr, HIDD);

    // chunked scan (fp32) + bf16 shadow
    scan_local<<<dim3(M_TOK/CHUNK), blk, 0, stream>>>(nu_log + l*STATE_D, th_log + l*STATE_D);
    scan_fix  <<<dim3(M_TOK/CHUNK), blk, 0, stream>>>(nu_log + l*STATE_D, th_log + l*STATE_D);

    // y = states @ Cw^T + D*h   (32768 x 256 x 512) -> g_y + g_yb
    mfma_gemm<0, 4><<<dim3(2, M_TOK/128), blk, 0, stream>>>(
        SB_BUB, 512, SB_CWB, l*131072, 512, SF_Y, SB_YB, HIDD,
        nullptr, SF_H, HIDD, Dv + l*HIDD, 512);

    // z = gelu(y @ Wh^T + bh)   (32768 x 1024 x 256) -> g_zb only
    mfma_gemm<1, 1><<<dim3(8, M_TOK/128), blk, 0, stream>>>(
        SB_YB, HIDD, SB_WHB, l*262144, STATE_D, -1, SB_ZB, MLPD,
        bh + l*MLPD, -1, 0, nullptr, STATE_D);

    // h = z @ Wo^T + bo + y     (32768 x 256 x 1024) -> g_h + g_hb
    mfma_gemm<0, 3><<<dim3(2, M_TOK/128), blk, 0, stream>>>(
        SB_ZB, MLPD, SB_WOB, l*262144, MLPD, SF_H, SB_HB, HIDD,
        bo + l*HIDD, SF_Y, HIDD, nullptr, MLPD);
  }

  // out = h @ out_W^T + out_b  (fp32 GEMM, fp32 store)
  out_gemm<<<dim3(OUTD/64, M_TOK/64), blk, 0, stream>>>(out_W, out_b, (float*)d_out);
}

// Round 4
// 1118.366 us; speedup vs baseline: 1.2950x; 1.0061x over previous
//
#include <hip/hip_runtime.h>
#include <hip/hip_bf16.h>
#include <math.h>

typedef __hip_bfloat16 bf16;
typedef __attribute__((ext_vector_type(8))) short bf16x8;   // 8 bf16 = 4 VGPR
typedef __attribute__((ext_vector_type(4))) float f32x4;    // MFMA acc

#define BATCH   16
#define SEQLEN  2048
#define INDIM   64
#define HIDD    256
#define STATE_D 256
#define MLPD    1024
#define OUTD    128
#define NLAYERS 4
#define M_TOK   (BATCH*SEQLEN)     // 32768 tokens
#define CHUNK   64
#define NCHUNK  (SEQLEN/CHUNK)     // 32 chunks per batch

// ---- fp32 masters (residual chain precision) -------------------------------
__device__ float g_h [(size_t)M_TOK*256];
__device__ float g_y [(size_t)M_TOK*256];
__device__ float g_bu[(size_t)M_TOK*512];
__device__ float g_carry[512*512];
// ---- bf16 shadows / packed weights (MFMA operands) -------------------------
__device__ bf16  g_hb [(size_t)M_TOK*256];
__device__ bf16  g_yb [(size_t)M_TOK*256];
__device__ bf16  g_bub[(size_t)M_TOK*512];
__device__ bf16  g_zb [(size_t)M_TOK*1024];
// per-layer packed weights (hoisted out of the layer loop)
__device__ bf16  g_Bnb[NLAYERS*512*256];    // B_norm: rows 0-255 re, 256-511 im
__device__ bf16  g_Cwb[NLAYERS*256*512];    // [Cre | -Cim]
__device__ bf16  g_Whb[NLAYERS*1024*256];
__device__ bf16  g_Wob[NLAYERS*256*1024];

#define SF_H  0
#define SF_Y  1
#define SF_BU 2
#define SB_HB  0
#define SB_YB  1
#define SB_BUB 2
#define SB_ZB  3
#define SB_BNB 4
#define SB_CWB 5
#define SB_WHB 6
#define SB_WOB 7

__device__ __forceinline__ float* buff(int sel){
  switch(sel){ case SF_H: return g_h; case SF_Y: return g_y; default: return g_bu; }
}
__device__ __forceinline__ bf16* bufb(int sel){
  switch(sel){
    case SB_HB:  return g_hb;  case SB_YB:  return g_yb;
    case SB_BUB: return g_bub; case SB_ZB:  return g_zb;
    case SB_BNB: return g_Bnb; case SB_CWB: return g_Cwb;
    case SB_WHB: return g_Whb; default:     return g_Wob; }
}

// async global->LDS, 16B per lane. LDS dest is wave-uniform base + lane*16.
__device__ __forceinline__ void gld_lds16(const void* g, void* l){
  __builtin_amdgcn_global_load_lds(
      (const __attribute__((address_space(1))) unsigned int*)g,
      (__attribute__((address_space(3))) unsigned int*)l, 16, 0, 0);
}

// Branch-free exact-GELU via Abramowitz-Stegun 7.1.26 erf (|err|<=1.5e-7,
// far below bf16 rounding). ~16 VALU incl v_rcp/v_exp, no divergence —
// replaces OCML erff (~60 inst with divergent range splits).
__device__ __forceinline__ float fast_gelu(float v){
  const float x  = v * 0.70710678118654752f;
  const float ax = fabsf(x);
  const float t  = __builtin_amdgcn_rcpf(fmaf(0.3275911f, ax, 1.0f));
  float p = fmaf(t, 1.061405429f, -1.453152027f);
  p = fmaf(t, p, 1.421413741f);
  p = fmaf(t, p, -0.284496736f);
  p = fmaf(t, p, 0.254829592f);
  p = p * t;
  const float e = __expf(-ax * ax);
  const float erf_ax = fmaf(-p, e, 1.0f);
  const float erf_x  = copysignf(erf_ax, x);
  return 0.5f * v * (1.0f + erf_x);
}

// ---------------------------------------------------------------------------
// MFMA GEMM: C[M,N] = act(A @ W^T + bias) (+res / +dscale*res)
// A: bf16 [M,K] lda;  W: bf16 [N,K] ldw (+wOff).  128x128 block, 4 waves, BK=32.
// 3-deep LDS ring + REGISTER PING-PONG pipeline (one barrier/iter):
//   iter t: barrier                       // certifies: reads of buf[t%3] done
//                                         //   (lgkm'd end of t-1) AND tile t+1
//                                         //   resident (vmcnt'd end of t-1)
//           STAGE(buf[t%3], tile t+3)     // refill freed buffer
//           ds_read fragNEXT <- tile t+1  // latency hidden under MFMA below
//           MFMA fragCUR (tile t)         // registers only
//           lgkmcnt(0)                    // fragNEXT ready (mostly covered)
//           vmcnt(4)                      // my tile t+2 loads done
// T2 swizzle (linear LDS dest + swizzled GLOBAL source, rule #21) keeps
// ds_read_b128 conflict-free (verified: 2.1M -> 0). XCD-chunked bijective
// blockIdx swizzle for L2 locality of the A panel.
// FLAGS: 1=bias  2=add res  4=add dscale[n]*res.  ACT: 1=exact GELU (fast erf).
// ---------------------------------------------------------------------------
template<int ACT, int FLAGS>
__global__ __launch_bounds__(256, 2) void mfma_gemm(
    int aSel, int lda, int wSel, int wOff, int ldw,
    int oFSel, int oBSel, int ldc,
    const float* __restrict__ bias,
    int rSel, int ldres,
    const float* __restrict__ dscale,
    int K)
{
  const bf16* A = bufb(aSel);
  const bf16* W = bufb(wSel) + wOff;
  float* OF = (oFSel >= 0) ? buff(oFSel) : nullptr;
  bf16*  OB = (oBSel >= 0) ? bufb(oBSel) : nullptr;
  const float* res = (rSel >= 0) ? buff(rSel) : nullptr;

  __shared__ __align__(16) unsigned short As[3*128*32];   // 3 x 8 KB
  __shared__ __align__(16) unsigned short Ws[3*128*32];   // 3 x 8 KB

  // ---- XCD-chunked bijective blockIdx swizzle (m204 formula) ----
  const int gx = gridDim.x;
  const int nwg = gx * gridDim.y;
  const int orig = blockIdx.y * gx + blockIdx.x;
  const int q = nwg >> 3, r = nwg & 7;
  const int xcd = orig & 7, idx = orig >> 3;
  const int wg = (xcd < r ? xcd*(q+1) : r*(q+1) + (xcd-r)*q) + idx;
  const int bx = wg % gx, by = wg / gx;

  const int tid  = threadIdx.x;
  const int row0 = by * 128, col0 = bx * 128;
  const int lane = tid & 63;
  const int m16  = lane & 15, quad = lane >> 4;
  const int wv   = tid >> 6;
  const int wm   = (wv & 1) * 64, wn = (wv >> 1) * 64;

  // staging: wave w, lane l -> LDS row w*16 + (l>>2), slot (l&3).
  // Source k-group is XOR-swizzled by row (same f for row and row+64).
  const int rlo = wv*16 + (lane >> 2);
  const int sg  = ((lane & 3) ^ ((rlo >> 1) & 3)) * 8;    // shorts
  const bf16* ga = &A[(size_t)(row0 + rlo)*lda + sg];
  const bf16* gw = &W[(size_t)(col0 + rlo)*ldw + sg];
  const size_t a64 = (size_t)64 * lda;
  const size_t w64 = (size_t)64 * ldw;

  auto STAGE = [&](int bb, int k0){
    unsigned short* Ab = As + bb*4096;
    unsigned short* Wb = Ws + bb*4096;
    gld_lds16(ga + k0,       Ab + wv*512);
    gld_lds16(ga + k0 + a64, Ab + 2048 + wv*512);
    gld_lds16(gw + k0,       Wb + wv*512);
    gld_lds16(gw + k0 + w64, Wb + 2048 + wv*512);
  };

  f32x4 acc[4][4] = {};
  const int nt = K >> 5;          // 8/16/32 for our shapes (even, >=4)

  bf16x8 fAa[4], fAw[4], fBa[4], fBw[4];   // two named fragment sets (rule #20)

  // ---- prologue: 3 tiles in flight; frag set A <- tile 0 ----
  STAGE(0, 0); STAGE(1, 32); STAGE(2, 64);           // 12 vm loads/wave
  asm volatile("s_waitcnt vmcnt(4)" ::: "memory");   // my tiles 0,1 done
  __builtin_amdgcn_s_barrier();                      // everyone's tiles 0,1 resident
  __builtin_amdgcn_sched_barrier(0);
  #pragma unroll
  for (int i = 0; i < 4; i++){
    const int rA = wm + 16*i + m16;
    const int rW = wn + 16*i + m16;
    fAa[i] = *reinterpret_cast<const bf16x8*>(&As[rA*32 + ((quad ^ ((rA>>1)&3))<<3)]);
    fAw[i] = *reinterpret_cast<const bf16x8*>(&Ws[rW*32 + ((quad ^ ((rW>>1)&3))<<3)]);
  }
  asm volatile("s_waitcnt lgkmcnt(0)" ::: "memory");
  __builtin_amdgcn_sched_barrier(0);

  int bS = 0, bR = 1;   // stage-target buf (t%3), read buf ((t+1)%3)

#define KITER(T, FMa, FMw, FRa, FRw)                                        \
  {                                                                         \
    __builtin_amdgcn_s_barrier();                                           \
    __builtin_amdgcn_sched_barrier(0);                                      \
    if ((T) + 3 < nt) STAGE(bS, ((T) + 3) << 5);                            \
    if ((T) + 1 < nt){                                                      \
      const unsigned short* Ab = As + bR*4096;                              \
      const unsigned short* Wb = Ws + bR*4096;                              \
      _Pragma("unroll")                                                     \
      for (int i = 0; i < 4; i++){                                          \
        const int rA = wm + 16*i + m16;                                     \
        const int rW = wn + 16*i + m16;                                     \
        FRa[i] = *reinterpret_cast<const bf16x8*>(&Ab[rA*32 + ((quad ^ ((rA>>1)&3))<<3)]); \
        FRw[i] = *reinterpret_cast<const bf16x8*>(&Wb[rW*32 + ((quad ^ ((rW>>1)&3))<<3)]); \
      }                                                                     \
    }                                                                       \
    __builtin_amdgcn_s_setprio(1);                                          \
    _Pragma("unroll")                                                       \
    for (int i = 0; i < 4; i++)                                             \
      _Pragma("unroll")                                                     \
      for (int j = 0; j < 4; j++)                                           \
        acc[i][j] = __builtin_amdgcn_mfma_f32_16x16x32_bf16(FMa[i], FMw[j], acc[i][j], 0, 0, 0); \
    __builtin_amdgcn_s_setprio(0);                                          \
    asm volatile("s_waitcnt lgkmcnt(0)" ::: "memory");                      \
    __builtin_amdgcn_sched_barrier(0);                                      \
    if ((T) + 3 < nt)      { asm volatile("s_waitcnt vmcnt(4)" ::: "memory"); } \
    else if ((T) + 2 < nt) { asm volatile("s_waitcnt vmcnt(0)" ::: "memory"); } \
    bS = (bS == 2) ? 0 : bS + 1;                                            \
    bR = (bR == 2) ? 0 : bR + 1;                                            \
  }

  for (int t = 0; t < nt; t += 2){
    KITER(t,     fAa, fAw, fBa, fBw);   // MFMA set A, prefetch set B
    KITER(t + 1, fBa, fBw, fAa, fAw);   // MFMA set B, prefetch set A
  }
#undef KITER

  // epilogue: C/D layout col=lane&15, row=quad*4+reg  (m89-verified)
  #pragma unroll
  for (int i = 0; i < 4; i++){
    #pragma unroll
    for (int j = 0; j < 4; j++){
      const int col = col0 + wn + 16*j + m16;
      #pragma unroll
      for (int r2 = 0; r2 < 4; r2++){
        const int row = row0 + wm + 16*i + quad*4 + r2;
        float v = acc[i][j][r2];
        if (FLAGS & 1) v += bias[col];
        if (ACT == 1)  v = fast_gelu(v);
        if (FLAGS & 2) v += res[(size_t)row*ldres + col];
        if (FLAGS & 4) v += dscale[col] * res[(size_t)row*ldres + col];
        const size_t o = (size_t)row*ldc + col;
        if (OF) OF[o] = v;
        if (OB) OB[o] = __float2bfloat16(v);
      }
    }
  }
}

// ---------------------------------------------------------------------------
// fp32 tiled GEMMs for the small ends (embed, out) — proven R12 structure.
// ---------------------------------------------------------------------------
__global__ __launch_bounds__(256) void emb_gemm(
    const float* __restrict__ x, const float* __restrict__ W,
    const float* __restrict__ b)
{
  __shared__ __align__(16) float Asx[16][68];
  __shared__ __align__(16) float Wsx[16][68];
  const int tid = threadIdx.x;
  const int tx = tid & 15, ty = tid >> 4;
  const int row0 = blockIdx.y * 64, col0 = blockIdx.x * 64;
  const int lc = tid & 15, lr = tid >> 4;
  float acc[4][4] = {};
  for (int k0 = 0; k0 < INDIM; k0 += 16){
    #pragma unroll
    for (int i = 0; i < 4; i++){
      Asx[lc][lr + 16*i] = x[(size_t)(row0 + lr + 16*i)*INDIM + k0 + lc];
      Wsx[lc][lr + 16*i] = W[(size_t)(col0 + lr + 16*i)*INDIM + k0 + lc];
    }
    __syncthreads();
    #pragma unroll
    for (int k = 0; k < 16; k++){
      float4 av = *reinterpret_cast<const float4*>(&Asx[k][ty*4]);
      float4 bv = *reinterpret_cast<const float4*>(&Wsx[k][tx*4]);
      float a[4] = {av.x, av.y, av.z, av.w};
      float b2[4] = {bv.x, bv.y, bv.z, bv.w};
      #pragma unroll
      for (int i = 0; i < 4; i++)
        #pragma unroll
        for (int j = 0; j < 4; j++)
          acc[i][j] = fmaf(a[i], b2[j], acc[i][j]);
    }
    __syncthreads();
  }
  #pragma unroll
  for (int i = 0; i < 4; i++){
    const int r = row0 + ty*4 + i;
    #pragma unroll
    for (int j = 0; j < 4; j++){
      const int cn = col0 + tx*4 + j;
      float v = acc[i][j] + b[cn];
      g_h [(size_t)r*HIDD + cn] = v;
      g_hb[(size_t)r*HIDD + cn] = __float2bfloat16(v);
    }
  }
}

__global__ __launch_bounds__(256) void out_gemm(
    const float* __restrict__ W, const float* __restrict__ b,
    float* __restrict__ out)
{
  __shared__ __align__(16) float Asx[16][68];
  __shared__ __align__(16) float Wsx[16][68];
  const int tid = threadIdx.x;
  const int tx = tid & 15, ty = tid >> 4;
  const int row0 = blockIdx.y * 64, col0 = blockIdx.x * 64;
  const int lc = tid & 15, lr = tid >> 4;
  float acc[4][4] = {};
  for (int k0 = 0; k0 < HIDD; k0 += 16){
    #pragma unroll
    for (int i = 0; i < 4; i++){
      Asx[lc][lr + 16*i] = g_h[(size_t)(row0 + lr + 16*i)*HIDD + k0 + lc];
      Wsx[lc][lr + 16*i] = W[(size_t)(col0 + lr + 16*i)*HIDD + k0 + lc];
    }
    __syncthreads();
    #pragma unroll
    for (int k = 0; k < 16; k++){
      float4 av = *reinterpret_cast<const float4*>(&Asx[k][ty*4]);
      float4 bv = *reinterpret_cast<const float4*>(&Wsx[k][tx*4]);
      float a[4] = {av.x, av.y, av.z, av.w};
      float b2[4] = {bv.x, bv.y, bv.z, bv.w};
      #pragma unroll
      for (int i = 0; i < 4; i++)
        #pragma unroll
        for (int j = 0; j < 4; j++)
          acc[i][j] = fmaf(a[i], b2[j], acc[i][j]);
    }
    __syncthreads();
  }
  #pragma unroll
  for (int i = 0; i < 4; i++){
    const int r = row0 + ty*4 + i;
    #pragma unroll
    for (int j = 0; j < 4; j++){
      const int cn = col0 + tx*4 + j;
      out[(size_t)r*OUTD + cn] = acc[i][j] + b[cn];
    }
  }
}

// ---------------------------------------------------------------------------
// lam_s = exp(-exp(nu)) * (cos(exp(th)) + i sin(exp(th)))
// ---------------------------------------------------------------------------
__device__ __forceinline__ void lam_of(const float* __restrict__ nu_log,
                                       const float* __restrict__ th_log,
                                       int s, float& lr, float& li)
{
  float nu  = expf(nu_log[s]);
  float th  = expf(th_log[s]);
  float mag = expf(-nu);
  lr = mag * cosf(th);
  li = mag * sinf(th);
}

// Carry-only local scan over 64-token chunks (fp32).
__global__ __launch_bounds__(256) void scan_local(
    const float* __restrict__ nu_log, const float* __restrict__ th_log)
{
  const int blk = blockIdx.x;          // chunk 0..511
  const int s   = threadIdx.x;
  float lr, li; lam_of(nu_log, th_log, s, lr, li);
  float ar = 0.f, ai = 0.f;
  size_t base = (size_t)blk * CHUNK * 512 + s;
  for (int t = 0; t < CHUNK; t++){
    float br = g_bu[base + (size_t)t*512];
    float bi = g_bu[base + (size_t)t*512 + 256];
    float nr = fmaf(lr, ar, fmaf(-li, ai, br));
    float ni = fmaf(lr, ai, fmaf( li, ar, bi));
    ar = nr; ai = ni;
  }
  g_carry[(size_t)blk*512 + s]       = ar;
  g_carry[(size_t)blk*512 + 256 + s] = ai;
}

// Prefix accumulate + full local re-scan seeded with prefix; bf16 emit only.
__global__ __launch_bounds__(256) void scan_fix(
    const float* __restrict__ nu_log, const float* __restrict__ th_log)
{
  const int blk = blockIdx.x;
  const int c   = blk & (NCHUNK - 1);
  const int s   = threadIdx.x;
  float lr, li; lam_of(nu_log, th_log, s, lr, li);
  float cr = 0.f, ci = 0.f;
  if (c > 0){
    float Tr = lr, Ti = li;
    #pragma unroll
    for (int i = 0; i < 6; i++){ float nr = Tr*Tr - Ti*Ti; Ti = 2.f*Tr*Ti; Tr = nr; }
    const int bstart = blk - c;
    for (int j = 0; j < c; j++){
      float er = g_carry[(size_t)(bstart + j)*512 + s];
      float ei = g_carry[(size_t)(bstart + j)*512 + 256 + s];
      float nr = fmaf(Tr, cr, fmaf(-Ti, ci, er));
      float ni = fmaf(Tr, ci, fmaf( Ti, cr, ei));
      cr = nr; ci = ni;
    }
  }
  // inclusive scan with incoming state (cr,ci)
  float ar = cr, ai = ci;
  size_t base = (size_t)blk * CHUNK * 512 + s;
  for (int t = 0; t < CHUNK; t++){
    size_t o = base + (size_t)t*512;
    float br = g_bu[o], bi = g_bu[o + 256];
    float nr = fmaf(lr, ar, fmaf(-li, ai, br));
    float ni = fmaf(lr, ai, fmaf( li, ar, bi));
    ar = nr; ai = ni;
    g_bub[o]       = __float2bfloat16(ar);
    g_bub[o + 256] = __float2bfloat16(ai);
  }
}

// Pack B_norm for ALL layers -> bf16 (per layer 512 x 256)
__global__ __launch_bounds__(256) void pack_B(
    const float* __restrict__ Bre, const float* __restrict__ Bim,
    const float* __restrict__ gl)
{
  int idx = blockIdx.x * 256 + threadIdx.x;      // 0..NLAYERS*65536-1
  int l = idx >> 16, within = idx & 65535;
  int s = within >> 8;
  float g = expf(gl[l*STATE_D + s]);
  g_Bnb[(size_t)l*131072 + within]         = __float2bfloat16(Bre[idx] * g);
  g_Bnb[(size_t)l*131072 + 65536 + within] = __float2bfloat16(Bim[idx] * g);
}

// Pack Cw for ALL layers -> bf16 (per layer 256 x 512): [Cre | -Cim]
__global__ __launch_bounds__(256) void pack_C(
    const float* __restrict__ Cre, const float* __restrict__ Cim)
{
  int idx = blockIdx.x * 256 + threadIdx.x;      // 0..NLAYERS*65536-1
  int l = idx >> 16, within = idx & 65535;
  int h = within >> 8, s = within & 255;
  g_Cwb[(size_t)l*131072 + (size_t)h*512 + s]       = __float2bfloat16( Cre[idx]);
  g_Cwb[(size_t)l*131072 + (size_t)h*512 + 256 + s] = __float2bfloat16(-Cim[idx]);
}

// Straight fp32 -> bf16 weight convert into selected buffer
__global__ __launch_bounds__(256) void conv_bf16(
    const float* __restrict__ src, int dstSel, int n)
{
  int i = blockIdx.x * 256 + threadIdx.x;
  if (i < n) bufb(dstSel)[i] = __float2bfloat16(src[i]);
}

// ---------------------------------------------------------------------------
extern "C" void kernel_launch(void* const* d_in, const int* in_sizes, int n_in,
                              void* d_out, int out_size, void* d_ws, size_t ws_size,
                              hipStream_t stream)
{
  (void)d_ws; (void)ws_size; (void)out_size; (void)n_in; (void)in_sizes;
  const float* x      = (const float*)d_in[0];
  const float* emb_W  = (const float*)d_in[1];
  const float* emb_b  = (const float*)d_in[2];
  const float* nu_log = (const float*)d_in[3];
  const float* th_log = (const float*)d_in[4];
  const float* ga_log = (const float*)d_in[5];
  const float* B_re   = (const float*)d_in[6];
  const float* B_im   = (const float*)d_in[7];
  const float* C_re   = (const float*)d_in[8];
  const float* C_im   = (const float*)d_in[9];
  const float* Dv     = (const float*)d_in[10];
  const float* Wh     = (const float*)d_in[11];
  const float* bh     = (const float*)d_in[12];
  const float* Wo     = (const float*)d_in[13];
  const float* bo     = (const float*)d_in[14];
  const float* out_W  = (const float*)d_in[15];
  const float* out_b  = (const float*)d_in[16];

  const dim3 blk(256);

  // ---- all weight packing upfront (independent of activations) ----
  pack_B<<<dim3(NLAYERS*256), blk, 0, stream>>>(B_re, B_im, ga_log);
  pack_C<<<dim3(NLAYERS*256), blk, 0, stream>>>(C_re, C_im);
  conv_bf16<<<dim3(NLAYERS*1024), blk, 0, stream>>>(Wh, SB_WHB, NLAYERS*262144);
  conv_bf16<<<dim3(NLAYERS*1024), blk, 0, stream>>>(Wo, SB_WOB, NLAYERS*262144);

  // embed: h = x @ emb_W^T + emb_b  (fp32 GEMM + bf16 shadow)
  emb_gemm<<<dim3(HIDD/64, M_TOK/64), blk, 0, stream>>>(x, emb_W, emb_b);

  for (int l = 0; l < NLAYERS; l++){
    // Bu = h @ Bn^T   (32768 x 512 x 256) -> g_bu fp32
    mfma_gemm<0, 0><<<dim3(4, M_TOK/128), blk, 0, stream>>>(
        SB_HB, HIDD, SB_BNB, l*131072, HIDD, SF_BU, -1, 512,
        nullptr, -1, 0, nullptr, HIDD);

    // chunked scan (fp32) + bf16 shadow
    scan_local<<<dim3(M_TOK/CHUNK), blk, 0, stream>>>(nu_log + l*STATE_D, th_log + l*STATE_D);
    scan_fix  <<<dim3(M_TOK/CHUNK), blk, 0, stream>>>(nu_log + l*STATE_D, th_log + l*STATE_D);

    // y = states @ Cw^T + D*h   (32768 x 256 x 512) -> g_y + g_yb
    mfma_gemm<0, 4><<<dim3(2, M_TOK/128), blk, 0, stream>>>(
        SB_BUB, 512, SB_CWB, l*131072, 512, SF_Y, SB_YB, HIDD,
        nullptr, SF_H, HIDD, Dv + l*HIDD, 512);

    // z = gelu(y @ Wh^T + bh)   (32768 x 1024 x 256) -> g_zb only
    mfma_gemm<1, 1><<<dim3(8, M_TOK/128), blk, 0, stream>>>(
        SB_YB, HIDD, SB_WHB, l*262144, STATE_D, -1, SB_ZB, MLPD,
        bh + l*MLPD, -1, 0, nullptr, STATE_D);

    // h = z @ Wo^T + bo + y     (32768 x 256 x 1024) -> g_h + g_hb
    mfma_gemm<0, 3><<<dim3(2, M_TOK/128), blk, 0, stream>>>(
        SB_ZB, MLPD, SB_WOB, l*262144, MLPD, SF_H, SB_HB, HIDD,
        bo + l*HIDD, SF_Y, HIDD, nullptr, MLPD);
  }

  // out = h @ out_W^T + out_b  (fp32 GEMM, fp32 store)
  out_gemm<<<dim3(OUTD/64, M_TOK/64), blk, 0, stream>>>(out_W, out_b, (float*)d_out);
}